// Round 1
// baseline (531.011 us; speedup 1.0000x reference)
//
#include <hip/hip_runtime.h>
#include <hip/hip_bf16.h>
#include <cstdint>

#define SDIM 8192
#define DIN  4096
#define DOUT 4096
#define KAUG 4224   // 4096 + 8*16 LoRA extension
#define NADP 8
#define RLORA 16

typedef __attribute__((ext_vector_type(8))) short short8;
typedef __attribute__((ext_vector_type(4))) float f32x4;

// ---------- conversion: f32 [rows][4096] -> bf16 [rows][4224] (first 4096 cols) ----------
__global__ void cvt_f32_to_bf16_aug(const float* __restrict__ src,
                                    __hip_bfloat16* __restrict__ dst,
                                    long total_elems) {
    long tid = (long)blockIdx.x * blockDim.x + threadIdx.x;
    long e = tid * 8;
    if (e >= total_elems) return;
    int s = (int)(e >> 12);        // row (4096 cols per src row)
    int k = (int)(e & 4095);
    const float4* p = (const float4*)(src + e);
    float4 v0 = p[0], v1 = p[1];
    union { __hip_bfloat16 h[8]; short8 v; } u;
    u.h[0] = __float2bfloat16(v0.x); u.h[1] = __float2bfloat16(v0.y);
    u.h[2] = __float2bfloat16(v0.z); u.h[3] = __float2bfloat16(v0.w);
    u.h[4] = __float2bfloat16(v1.x); u.h[5] = __float2bfloat16(v1.y);
    u.h[6] = __float2bfloat16(v1.z); u.h[7] = __float2bfloat16(v1.w);
    *(short8*)(dst + (size_t)s * KAUG + k) = u.v;
}

// ---------- B tail: Waug[n][4096 + l*16 + r] = B0[l][n][r] ----------
__global__ void cvt_btail(const float* __restrict__ B0,
                          __hip_bfloat16* __restrict__ waug) {
    int t = blockIdx.x * blockDim.x + threadIdx.x;   // 4096*128
    if (t >= DOUT * NADP * RLORA) return;
    int n = t >> 7, c = t & 127;
    int l = c >> 4, r = c & 15;
    float v = B0[((size_t)l * DOUT + n) * RLORA + r];
    waug[(size_t)n * KAUG + 4096 + c] = __float2bfloat16(v);
}

// ---------- per-token XA: xaug[s][4096 + l*16 + r] = (l==idx[s]) ? 2*<x[s],A[l][r]> : 0 ----------
__global__ __launch_bounds__(256) void lora_xa(const float* __restrict__ x,
                         const float* __restrict__ A,
                         const int* __restrict__ widx,
                         __hip_bfloat16* __restrict__ xaug) {
    int s = blockIdx.x;
    int l = widx[s];
    __shared__ float xs[DIN];
    __shared__ float red[RLORA];
    const float4* x4 = (const float4*)(x + (size_t)s * DIN);
    float4* xs4 = (float4*)xs;
    for (int i = threadIdx.x; i < DIN / 4; i += 256) xs4[i] = x4[i];
    __syncthreads();
    int r = threadIdx.x >> 4, j = threadIdx.x & 15;
    const float4* A4 = (const float4*)(A + ((size_t)l * RLORA + r) * DIN);
    float sum = 0.f;
    #pragma unroll 8
    for (int i = 0; i < 64; ++i) {
        float4 av = A4[j + 16 * i];
        float4 xv = xs4[j + 16 * i];
        sum += av.x * xv.x + av.y * xv.y + av.z * xv.z + av.w * xv.w;
    }
    #pragma unroll
    for (int m = 1; m < 16; m <<= 1) sum += __shfl_xor(sum, m, 64);
    if (j == 0) red[r] = sum * 2.0f;   // SCALING folded in here
    __syncthreads();
    if (threadIdx.x < NADP * RLORA) {
        int lp = threadIdx.x >> 4, rr = threadIdx.x & 15;
        float v = (lp == l) ? red[rr] : 0.0f;
        xaug[(size_t)s * KAUG + 4096 + threadIdx.x] = __float2bfloat16(v);
    }
}

// ---------- main GEMM: out = Xaug @ Waug^T + bias ; 128x128 tile, BK=64 ----------
__global__ __launch_bounds__(256) void gemm_aug(const __hip_bfloat16* __restrict__ Xa,
                                                const __hip_bfloat16* __restrict__ Wa,
                                                const float* __restrict__ bias,
                                                float* __restrict__ out) {
    __shared__ __align__(16) char smem[32768];  // As 16KB | Bs 16KB  ([128 rows][64 bf16] each)
    char* As = smem;
    char* Bs = smem + 16384;

    const int t = threadIdx.x;
    const int lane = t & 63, wave = t >> 6;
    const int rowA0 = blockIdx.y * 128;   // M tile
    const int colB0 = blockIdx.x * 128;   // N tile

    // staging geometry: tile = 16KB = 4 calls x (256 lanes x 16B)
    // LDS slot (linear) -> source chunk swizzled so that read-side XOR lands right (rule #21)
    const __hip_bfloat16* gA[4];
    const __hip_bfloat16* gB[4];
    #pragma unroll
    for (int i = 0; i < 4; ++i) {
        int slot = i * 4096 + wave * 1024 + lane * 16;
        int r = slot >> 7;               // LDS row (128B per row)
        int c = (slot >> 4) & 7;         // 16B chunk within row
        int cp = c ^ (r & 7);            // swizzled source chunk
        gA[i] = Xa + (size_t)(rowA0 + r) * KAUG + cp * 8;
        gB[i] = Wa + (size_t)(colB0 + r) * KAUG + cp * 8;
    }

    const int wm = wave >> 1, wn = wave & 1;   // 2x2 wave grid, 64x64 each
    const int lr = lane & 15, lk = lane >> 4;

    f32x4 zero = {0.f, 0.f, 0.f, 0.f};
    f32x4 acc[4][4];
    #pragma unroll
    for (int m = 0; m < 4; ++m)
        #pragma unroll
        for (int n = 0; n < 4; ++n) acc[m][n] = zero;

    for (int kt = 0; kt < KAUG / 64; ++kt) {
        #pragma unroll
        for (int i = 0; i < 4; ++i) {
            __builtin_amdgcn_global_load_lds((const uint32_t*)(gA[i] + kt * 64),
                                             (uint32_t*)(As + i * 4096 + wave * 1024), 16, 0, 0);
            __builtin_amdgcn_global_load_lds((const uint32_t*)(gB[i] + kt * 64),
                                             (uint32_t*)(Bs + i * 4096 + wave * 1024), 16, 0, 0);
        }
        __syncthreads();   // drains vmcnt(0): LDS tiles ready
        #pragma unroll
        for (int kk = 0; kk < 2; ++kk) {
            short8 af[4], bf[4];
            #pragma unroll
            for (int m = 0; m < 4; ++m) {
                int row = wm * 64 + m * 16 + lr;
                int cc = (kk * 4 + lk) ^ (row & 7);
                af[m] = *(const short8*)(As + row * 128 + cc * 16);
            }
            #pragma unroll
            for (int n = 0; n < 4; ++n) {
                int row = wn * 64 + n * 16 + lr;
                int cc = (kk * 4 + lk) ^ (row & 7);
                bf[n] = *(const short8*)(Bs + row * 128 + cc * 16);
            }
            #pragma unroll
            for (int m = 0; m < 4; ++m)
                #pragma unroll
                for (int n = 0; n < 4; ++n)
                    acc[m][n] = __builtin_amdgcn_mfma_f32_16x16x32_bf16(af[m], bf[n], acc[m][n], 0, 0, 0);
        }
        __syncthreads();   // protect LDS before next stage
    }

    // epilogue: C/D map col=lane&15, row=(lane>>4)*4+reg  [m89]
    #pragma unroll
    for (int n = 0; n < 4; ++n) {
        int col = colB0 + wn * 64 + n * 16 + lr;
        float bv = bias[col];
        #pragma unroll
        for (int m = 0; m < 4; ++m) {
            int row0 = rowA0 + wm * 64 + m * 16 + lk * 4;
            #pragma unroll
            for (int j = 0; j < 4; ++j) {
                out[(size_t)(row0 + j) * DOUT + col] = acc[m][n][j] + bv;
            }
        }
    }
}

extern "C" void kernel_launch(void* const* d_in, const int* in_sizes, int n_in,
                              void* d_out, int out_size, void* d_ws, size_t ws_size,
                              hipStream_t stream) {
    const float* x      = (const float*)d_in[0];
    const float* weight = (const float*)d_in[1];
    const float* bias   = (const float*)d_in[2];
    const float* A_buf  = (const float*)d_in[3];
    const float* B_buf  = (const float*)d_in[4];  // [1, L, d_out, r]
    const int*   widx   = (const int*)d_in[5];
    float* out = (float*)d_out;

    // workspace layout
    __hip_bfloat16* xaug = (__hip_bfloat16*)d_ws;                       // [8192][4224] = 69.2 MB
    __hip_bfloat16* waug = (__hip_bfloat16*)((char*)d_ws + (size_t)SDIM * KAUG * 2); // [4096][4224] = 34.6 MB

    // 1) x -> bf16 into xaug[:, 0:4096]
    {
        long total = (long)SDIM * DIN;
        int blocks = (int)((total / 8 + 255) / 256);
        cvt_f32_to_bf16_aug<<<blocks, 256, 0, stream>>>(x, xaug, total);
    }
    // 2) weight -> bf16 into waug[:, 0:4096]
    {
        long total = (long)DOUT * DIN;
        int blocks = (int)((total / 8 + 255) / 256);
        cvt_f32_to_bf16_aug<<<blocks, 256, 0, stream>>>(weight, waug, total);
    }
    // 3) B tail into waug[:, 4096:4224]
    {
        int total = DOUT * NADP * RLORA;
        cvt_btail<<<(total + 255) / 256, 256, 0, stream>>>(B_buf, waug);
    }
    // 4) per-token masked-scaled XA into xaug[:, 4096:4224]
    lora_xa<<<SDIM, 256, 0, stream>>>(x, A_buf, widx, xaug);

    // 5) fused GEMM + bias
    dim3 grid(DOUT / 128, SDIM / 128);
    gemm_aug<<<grid, 256, 0, stream>>>(xaug, waug, bias, out);
}

// Round 2
// 363.943 us; speedup vs baseline: 1.4590x; 1.4590x over previous
//
#include <hip/hip_runtime.h>
#include <hip/hip_bf16.h>
#include <cstdint>

#define SDIM 8192
#define DIN  4096
#define DOUT 4096
#define KAUG 4224   // 4096 + 8*16 LoRA extension
#define NADP 8
#define RLORA 16
#define NT 66       // K-tiles of 64

typedef __attribute__((ext_vector_type(8))) short short8;
typedef __attribute__((ext_vector_type(4))) float f32x4;

// ---------- conversion: f32 [rows][4096] -> bf16 [rows][4224] (first 4096 cols) ----------
__global__ void cvt_f32_to_bf16_aug(const float* __restrict__ src,
                                    __hip_bfloat16* __restrict__ dst,
                                    long total_elems) {
    long tid = (long)blockIdx.x * blockDim.x + threadIdx.x;
    long e = tid * 8;
    if (e >= total_elems) return;
    int s = (int)(e >> 12);
    int k = (int)(e & 4095);
    const float4* p = (const float4*)(src + e);
    float4 v0 = p[0], v1 = p[1];
    union { __hip_bfloat16 h[8]; short8 v; } u;
    u.h[0] = __float2bfloat16(v0.x); u.h[1] = __float2bfloat16(v0.y);
    u.h[2] = __float2bfloat16(v0.z); u.h[3] = __float2bfloat16(v0.w);
    u.h[4] = __float2bfloat16(v1.x); u.h[5] = __float2bfloat16(v1.y);
    u.h[6] = __float2bfloat16(v1.z); u.h[7] = __float2bfloat16(v1.w);
    *(short8*)(dst + (size_t)s * KAUG + k) = u.v;
}

// ---------- B tail: Waug[n][4096 + l*16 + r] = B0[l][n][r] ----------
__global__ void cvt_btail(const float* __restrict__ B0,
                          __hip_bfloat16* __restrict__ waug) {
    int t = blockIdx.x * blockDim.x + threadIdx.x;
    if (t >= DOUT * NADP * RLORA) return;
    int n = t >> 7, c = t & 127;
    int l = c >> 4, r = c & 15;
    float v = B0[((size_t)l * DOUT + n) * RLORA + r];
    waug[(size_t)n * KAUG + 4096 + c] = __float2bfloat16(v);
}

// ---------- fused: x row -> bf16 into xaug[:,0:4096] AND XA tail ----------
__global__ __launch_bounds__(256) void lora_xa_cvt(const float* __restrict__ x,
                         const float* __restrict__ A,
                         const int* __restrict__ widx,
                         __hip_bfloat16* __restrict__ xaug) {
    int s = blockIdx.x;
    int l = widx[s];
    __shared__ float xs[DIN];
    __shared__ float red[RLORA];
    const float4* x4 = (const float4*)(x + (size_t)s * DIN);
    float4* xs4 = (float4*)xs;
    #pragma unroll
    for (int jj = 0; jj < 2; ++jj) {
        int idx = jj * 512 + threadIdx.x * 2;   // float4 index, pairs
        float4 v0 = x4[idx], v1 = x4[idx + 1];
        xs4[idx] = v0; xs4[idx + 1] = v1;
        union { __hip_bfloat16 h[8]; short8 v; } u;
        u.h[0] = __float2bfloat16(v0.x); u.h[1] = __float2bfloat16(v0.y);
        u.h[2] = __float2bfloat16(v0.z); u.h[3] = __float2bfloat16(v0.w);
        u.h[4] = __float2bfloat16(v1.x); u.h[5] = __float2bfloat16(v1.y);
        u.h[6] = __float2bfloat16(v1.z); u.h[7] = __float2bfloat16(v1.w);
        *(short8*)(xaug + (size_t)s * KAUG + idx * 4) = u.v;
    }
    __syncthreads();
    int r = threadIdx.x >> 4, j = threadIdx.x & 15;
    const float4* A4 = (const float4*)(A + ((size_t)l * RLORA + r) * DIN);
    float sum = 0.f;
    #pragma unroll 8
    for (int i = 0; i < 64; ++i) {
        float4 av = A4[j + 16 * i];
        float4 xv = xs4[j + 16 * i];
        sum += av.x * xv.x + av.y * xv.y + av.z * xv.z + av.w * xv.w;
    }
    #pragma unroll
    for (int m = 1; m < 16; m <<= 1) sum += __shfl_xor(sum, m, 64);
    if (j == 0) red[r] = sum * 2.0f;   // SCALING folded in
    __syncthreads();
    if (threadIdx.x < NADP * RLORA) {
        int lp = threadIdx.x >> 4, rr = threadIdx.x & 15;
        float v = (lp == l) ? red[rr] : 0.0f;
        xaug[(size_t)s * KAUG + 4096 + threadIdx.x] = __float2bfloat16(v);
    }
}

// ---------- 256x256 8-phase GEMM: out = Xaug @ Waug^T + bias ----------
// 8 waves (2M x 4N), per-wave 128x64, BK=64, LDS 128KB double-buffered.
// Schedule: phase = {ds_read subtile || stage half-tile || bar || lgkmcnt(0) ||
//   setprio(1) 16xMFMA setprio(0) || bar}; counted vmcnt(4) at phases 4 and 8.
__global__ __launch_bounds__(512, 2) void gemm8(const __hip_bfloat16* __restrict__ Xa,
                                                const __hip_bfloat16* __restrict__ Wa,
                                                const float* __restrict__ bias,
                                                float* __restrict__ out) {
    // layout: buf0.A [0,32K) buf0.B [32K,64K) buf1.A [64K,96K) buf1.B [96K,128K)
    __shared__ __attribute__((aligned(16))) char lds[131072];

    const int tid = threadIdx.x;
    const int lane = tid & 63, wave = tid >> 6;
    const int wm = wave >> 2, wn = wave & 3;
    const int lr = lane & 15, lk = lane >> 4;

    // bijective XCD swizzle (512 blocks, 512 % 8 == 0)
    int wg = blockIdx.x;
    int swz = (wg & 7) * 64 + (wg >> 3);
    int bm = swz >> 4, bn = swz & 15;
    const int rowA0 = bm * 256, colB0 = bn * 256;

    // staging: per call 2 x global_load_lds, 16B/lane, linear LDS dest,
    // inverse-swizzled global source (rule #21). LDS[r][c] = G[r][c ^ (r&7)].
    const int sr = tid >> 3;                 // row within 64-row unit
    const int cp = (tid & 7) ^ (sr & 7);     // swizzled source 16B-chunk
    const __hip_bfloat16* srcA = Xa + (size_t)(rowA0 + sr) * KAUG + cp * 8;
    const __hip_bfloat16* srcB = Wa + (size_t)(colB0 + sr) * KAUG + cp * 8;

    auto STAGE = [&](int buf, int mat, int half, int kt) {
        const __hip_bfloat16* s0 = (mat ? srcB : srcA) + (size_t)(half * 128) * KAUG + kt * 64;
        char* d = lds + buf * 65536 + mat * 32768 + half * 16384 + tid * 16;
        __builtin_amdgcn_global_load_lds((const uint32_t*)s0, (uint32_t*)d, 16, 0, 0);
        __builtin_amdgcn_global_load_lds((const uint32_t*)(s0 + (size_t)64 * KAUG),
                                         (uint32_t*)(d + 8192), 16, 0, 0);
    };

    f32x4 acc[8][4] = {};
    short8 a[4][2], blo[2][2], bhi[2][2];

    auto LDA4 = [&](short8 (&af)[4][2], int buf, int mbase) {
        const char* base = lds + buf * 65536;
        #pragma unroll
        for (int m = 0; m < 4; ++m)
            #pragma unroll
            for (int kk = 0; kk < 2; ++kk) {
                int row = wm * 128 + (mbase + m) * 16 + lr;
                int cc = (kk * 4 + lk) ^ (row & 7);
                af[m][kk] = *(const short8*)(base + row * 128 + cc * 16);
            }
    };
    auto LDB2 = [&](short8 (&bf)[2][2], int buf, int nbase) {
        const char* base = lds + buf * 65536 + 32768;
        #pragma unroll
        for (int n = 0; n < 2; ++n)
            #pragma unroll
            for (int kk = 0; kk < 2; ++kk) {
                int row = wn * 64 + (nbase + n) * 16 + lr;
                int cc = (kk * 4 + lk) ^ (row & 7);
                bf[n][kk] = *(const short8*)(base + row * 128 + cc * 16);
            }
    };

#define MMQ(AF, BF, MB, NB)                                                        \
    do {                                                                           \
        __builtin_amdgcn_s_setprio(1);                                             \
        _Pragma("unroll")                                                          \
        for (int m = 0; m < 4; ++m)                                                \
            _Pragma("unroll")                                                      \
            for (int n = 0; n < 2; ++n)                                            \
                _Pragma("unroll")                                                  \
                for (int kk = 0; kk < 2; ++kk)                                     \
                    acc[(MB) + m][(NB) + n] = __builtin_amdgcn_mfma_f32_16x16x32_bf16( \
                        AF[m][kk], BF[n][kk], acc[(MB) + m][(NB) + n], 0, 0, 0);   \
        __builtin_amdgcn_s_setprio(0);                                             \
    } while (0)

#define BAR() __builtin_amdgcn_s_barrier()
#define LGK0() asm volatile("s_waitcnt lgkmcnt(0)")
#define VM4() asm volatile("s_waitcnt vmcnt(4)" ::: "memory")

    // prologue: buf0 <- t0 (full), buf1.B <- t1
    STAGE(0, 0, 0, 0); STAGE(0, 0, 1, 0);
    STAGE(0, 1, 0, 0); STAGE(0, 1, 1, 0);
    STAGE(1, 1, 0, 1); STAGE(1, 1, 1, 1);
    VM4();   // buf0 landed; buf1.B (4) in flight
    BAR();

    #pragma unroll 1
    for (int i = 0; i < NT / 2; ++i) {
        int t1 = 2 * i + 1;
        int t2 = 2 * i + 2; if (t2 > NT - 1) t2 = NT - 1;   // clamp keeps vmcnt uniform
        int t3 = 2 * i + 3; if (t3 > NT - 1) t3 = NT - 1;
        // P1: compute buf0 Q(0..3, 0..1); stage buf1.A.h0 <- t1
        LDA4(a, 0, 0); LDB2(blo, 0, 0);
        STAGE(1, 0, 0, t1);
        BAR(); LGK0();
        MMQ(a, blo, 0, 0);
        BAR();
        // P2: Q(0..3, 2..3); stage buf1.A.h1 <- t1
        LDB2(bhi, 0, 2);
        STAGE(1, 0, 1, t1);
        BAR(); LGK0();
        MMQ(a, bhi, 0, 2);
        BAR();
        // P3: Q(4..7, 2..3); stage buf0.B.h0 <- t2  (buf0.B consumed by end P2)
        LDA4(a, 0, 4);
        STAGE(0, 1, 0, t2);
        BAR(); LGK0();
        MMQ(a, bhi, 4, 2);
        BAR();
        // P4: Q(4..7, 0..1); stage buf0.B.h1 <- t2; vmcnt(4) -> buf1 ready
        STAGE(0, 1, 1, t2);
        VM4();
        BAR();
        MMQ(a, blo, 4, 0);
        BAR();
        // P5: compute buf1 Q(0..3, 0..1); stage buf0.A.h0 <- t2 (buf0.A consumed by end P3)
        LDA4(a, 1, 0); LDB2(blo, 1, 0);
        STAGE(0, 0, 0, t2);
        BAR(); LGK0();
        MMQ(a, blo, 0, 0);
        BAR();
        // P6: Q(0..3, 2..3); stage buf0.A.h1 <- t2
        LDB2(bhi, 1, 2);
        STAGE(0, 0, 1, t2);
        BAR(); LGK0();
        MMQ(a, bhi, 0, 2);
        BAR();
        // P7: Q(4..7, 2..3); stage buf1.B.h0 <- t3 (buf1.B consumed by end P6)
        LDA4(a, 1, 4);
        STAGE(1, 1, 0, t3);
        BAR(); LGK0();
        MMQ(a, bhi, 4, 2);
        BAR();
        // P8: Q(4..7, 0..1); stage buf1.B.h1 <- t3; vmcnt(4) -> buf0 (t2) ready
        STAGE(1, 1, 1, t3);
        VM4();
        BAR();
        MMQ(a, blo, 4, 0);
        BAR();
    }

    // epilogue: C/D map col=lane&15, row=(lane>>4)*4+j  [m89]
    #pragma unroll
    for (int n = 0; n < 4; ++n) {
        int col = colB0 + wn * 64 + n * 16 + lr;
        float bv = bias[col];
        #pragma unroll
        for (int m = 0; m < 8; ++m) {
            int row0 = rowA0 + wm * 128 + m * 16 + lk * 4;
            #pragma unroll
            for (int j = 0; j < 4; ++j) {
                out[(size_t)(row0 + j) * DOUT + col] = acc[m][n][j] + bv;
            }
        }
    }
#undef MMQ
#undef BAR
#undef LGK0
#undef VM4
}

extern "C" void kernel_launch(void* const* d_in, const int* in_sizes, int n_in,
                              void* d_out, int out_size, void* d_ws, size_t ws_size,
                              hipStream_t stream) {
    const float* x      = (const float*)d_in[0];
    const float* weight = (const float*)d_in[1];
    const float* bias   = (const float*)d_in[2];
    const float* A_buf  = (const float*)d_in[3];
    const float* B_buf  = (const float*)d_in[4];
    const int*   widx   = (const int*)d_in[5];
    float* out = (float*)d_out;

    __hip_bfloat16* xaug = (__hip_bfloat16*)d_ws;                                    // [8192][4224]
    __hip_bfloat16* waug = (__hip_bfloat16*)((char*)d_ws + (size_t)SDIM * KAUG * 2); // [4096][4224]

    // weight -> bf16 into waug[:, 0:4096]
    {
        long total = (long)DOUT * DIN;
        int blocks = (int)((total / 8 + 255) / 256);
        cvt_f32_to_bf16_aug<<<blocks, 256, 0, stream>>>(weight, waug, total);
    }
    // B tail into waug[:, 4096:4224]
    {
        int total = DOUT * NADP * RLORA;
        cvt_btail<<<(total + 255) / 256, 256, 0, stream>>>(B_buf, waug);
    }
    // fused x conversion + per-token masked-scaled XA
    lora_xa_cvt<<<SDIM, 256, 0, stream>>>(x, A_buf, widx, xaug);

    // 8-phase 256^2 GEMM + bias
    gemm8<<<(SDIM / 256) * (DOUT / 256), 512, 0, stream>>>(xaug, waug, bias, out);
}

// Round 3
// 319.940 us; speedup vs baseline: 1.6597x; 1.1375x over previous
//
#include <hip/hip_runtime.h>
#include <hip/hip_bf16.h>
#include <cstdint>

#define SDIM 8192
#define DIN  4096
#define DOUT 4096
#define KAUG 4224   // 4096 + 8*16 LoRA extension
#define NADP 8
#define RLORA 16
#define NT 66       // K-tiles of 64

typedef __attribute__((ext_vector_type(8))) short short8;
typedef __attribute__((ext_vector_type(4))) float f32x4;

// ---------- conversion: f32 [rows][4096] -> bf16 [rows][KAUG] (first 4096 cols) ----------
__global__ void cvt_f32_to_bf16_aug(const float* __restrict__ src,
                                    __hip_bfloat16* __restrict__ dst,
                                    long total_elems) {
    long tid = (long)blockIdx.x * blockDim.x + threadIdx.x;
    long e = tid * 8;
    if (e >= total_elems) return;
    int s = (int)(e >> 12);
    int k = (int)(e & 4095);
    const float4* p = (const float4*)(src + e);
    float4 v0 = p[0], v1 = p[1];
    union { __hip_bfloat16 h[8]; short8 v; } u;
    u.h[0] = __float2bfloat16(v0.x); u.h[1] = __float2bfloat16(v0.y);
    u.h[2] = __float2bfloat16(v0.z); u.h[3] = __float2bfloat16(v0.w);
    u.h[4] = __float2bfloat16(v1.x); u.h[5] = __float2bfloat16(v1.y);
    u.h[6] = __float2bfloat16(v1.z); u.h[7] = __float2bfloat16(v1.w);
    *(short8*)(dst + (size_t)s * KAUG + k) = u.v;
}

// ---------- B tail into waug + A_all f32->bf16 into abf ----------
__global__ void prep_small(const float* __restrict__ B0, const float* __restrict__ A,
                           __hip_bfloat16* __restrict__ waug, __hip_bfloat16* __restrict__ abf) {
    int t = blockIdx.x * 256 + threadIdx.x;
    if (blockIdx.x < 2048) {           // btail: DOUT*128 elems
        int n = t >> 7, c = t & 127;
        int l = c >> 4, r = c & 15;
        waug[(size_t)n * KAUG + 4096 + c] =
            __float2bfloat16(B0[((size_t)l * DOUT + n) * RLORA + r]);
    } else {                           // A cvt: 128*4096 elems, 8/thread
        long e = (long)(t - 2048 * 256) * 8;
        const float4* p = (const float4*)(A + e);
        float4 v0 = p[0], v1 = p[1];
        union { __hip_bfloat16 h[8]; short8 v; } u;
        u.h[0] = __float2bfloat16(v0.x); u.h[1] = __float2bfloat16(v0.y);
        u.h[2] = __float2bfloat16(v0.z); u.h[3] = __float2bfloat16(v0.w);
        u.h[4] = __float2bfloat16(v1.x); u.h[5] = __float2bfloat16(v1.y);
        u.h[6] = __float2bfloat16(v1.z); u.h[7] = __float2bfloat16(v1.w);
        *(short8*)(abf + e) = u.v;
    }
}

// ---------- XA_all split-K mini-GEMM: part[kc][8192][128] = Xa[:, kc*1024:+1024] @ Ab^T ----------
__global__ __launch_bounds__(256) void xa_gemm(const __hip_bfloat16* __restrict__ Xa,
                                               const __hip_bfloat16* __restrict__ Ab,
                                               float* __restrict__ part) {
    __shared__ __attribute__((aligned(16))) char sm[32768];
    char* Xs = sm;              // [128][64] bf16
    char* As = sm + 16384;      // [128][64] bf16
    const int tid = threadIdx.x, lane = tid & 63, wave = tid >> 6;
    const int mt = blockIdx.x >> 2, kc = blockIdx.x & 3;
    const int row0 = mt * 128, k0 = kc * 1024;
    const int sr = tid >> 3;                 // 0..31
    const int cp = (tid & 7) ^ (sr & 7);
    const __hip_bfloat16* gX = Xa + (size_t)(row0 + sr) * KAUG + k0 + cp * 8;
    const __hip_bfloat16* gA = Ab + (size_t)sr * DIN + k0 + cp * 8;
    const int lr = lane & 15, lk = lane >> 4;
    f32x4 acc[2][8] = {};
    for (int kt = 0; kt < 16; ++kt) {
        #pragma unroll
        for (int i = 0; i < 4; ++i) {
            __builtin_amdgcn_global_load_lds((const uint32_t*)(gX + (size_t)(32 * i) * KAUG + kt * 64),
                                             (uint32_t*)(Xs + i * 4096 + tid * 16), 16, 0, 0);
            __builtin_amdgcn_global_load_lds((const uint32_t*)(gA + (size_t)(32 * i) * DIN + kt * 64),
                                             (uint32_t*)(As + i * 4096 + tid * 16), 16, 0, 0);
        }
        __syncthreads();
        #pragma unroll
        for (int kk = 0; kk < 2; ++kk) {
            short8 av[2], bv[8];
            #pragma unroll
            for (int m = 0; m < 2; ++m) {
                int row = wave * 32 + m * 16 + lr;
                int cc = (kk * 4 + lk) ^ (row & 7);
                av[m] = *(const short8*)(Xs + row * 128 + cc * 16);
            }
            #pragma unroll
            for (int n = 0; n < 8; ++n) {
                int row = n * 16 + lr;
                int cc = (kk * 4 + lk) ^ (row & 7);
                bv[n] = *(const short8*)(As + row * 128 + cc * 16);
            }
            #pragma unroll
            for (int m = 0; m < 2; ++m)
                #pragma unroll
                for (int n = 0; n < 8; ++n)
                    acc[m][n] = __builtin_amdgcn_mfma_f32_16x16x32_bf16(av[m], bv[n], acc[m][n], 0, 0, 0);
        }
        __syncthreads();
    }
    #pragma unroll
    for (int n = 0; n < 8; ++n) {
        int col = n * 16 + lr;
        #pragma unroll
        for (int m = 0; m < 2; ++m) {
            int r0 = wave * 32 + m * 16 + lk * 4;
            #pragma unroll
            for (int j = 0; j < 4; ++j)
                part[((size_t)kc << 20) + (size_t)(row0 + r0 + j) * 128 + col] = acc[m][n][j];
        }
    }
}

// ---------- reduce split-K partials, mask by adapter, scale, cvt -> xaug tail ----------
__global__ void xa_reduce(const float* __restrict__ part, const int* __restrict__ widx,
                          __hip_bfloat16* __restrict__ xaug) {
    int t = blockIdx.x * 256 + threadIdx.x;   // < 8192*128
    int s = t >> 7, c = t & 127;
    float sum = part[t] + part[(1 << 20) + t] + part[(2 << 20) + t] + part[(3 << 20) + t];
    int l = widx[s];
    float v = ((c >> 4) == l) ? 2.0f * sum : 0.0f;
    xaug[(size_t)s * KAUG + 4096 + c] = __float2bfloat16(v);
}

// ---------- 256x256 8-phase GEMM: out = Xaug @ Waug^T + bias ----------
// 8 waves (2M x 4N), per-wave 128x64, BK=64, LDS 128KB double-buffered.
// Staging at earliest WAR-legal phase; counted vmcnt(6) at P4/P8 (3 half-tiles in flight).
__global__ __launch_bounds__(512, 2) void gemm8(const __hip_bfloat16* __restrict__ Xa,
                                                const __hip_bfloat16* __restrict__ Wa,
                                                const float* __restrict__ bias,
                                                float* __restrict__ out) {
    // layout: buf0.A [0,32K) buf0.B [32K,64K) buf1.A [64K,96K) buf1.B [96K,128K)
    __shared__ __attribute__((aligned(16))) char lds[131072];

    const int tid = threadIdx.x;
    const int lane = tid & 63, wave = tid >> 6;
    const int wm = wave >> 2, wn = wave & 3;
    const int lr = lane & 15, lk = lane >> 4;

    // bijective XCD swizzle (512 blocks, 512 % 8 == 0)
    int wg = blockIdx.x;
    int swz = (wg & 7) * 64 + (wg >> 3);
    int bm = swz >> 4, bn = swz & 15;
    const int rowA0 = bm * 256, colB0 = bn * 256;

    // staging: linear LDS dest, inverse-swizzled global source (rule #21).
    // LDS[r][c16] = G[r][c16 ^ (r&7)]
    const int sr = tid >> 3;
    const int cp = (tid & 7) ^ (sr & 7);
    const __hip_bfloat16* srcA = Xa + (size_t)(rowA0 + sr) * KAUG + cp * 8;
    const __hip_bfloat16* srcB = Wa + (size_t)(colB0 + sr) * KAUG + cp * 8;

    auto STAGE = [&](int buf, int mat, int half, int kt) {
        const __hip_bfloat16* s0 = (mat ? srcB : srcA) + (size_t)(half * 128) * KAUG + kt * 64;
        char* d = lds + buf * 65536 + mat * 32768 + half * 16384 + tid * 16;
        __builtin_amdgcn_global_load_lds((const uint32_t*)s0, (uint32_t*)d, 16, 0, 0);
        __builtin_amdgcn_global_load_lds((const uint32_t*)(s0 + (size_t)64 * KAUG),
                                         (uint32_t*)(d + 8192), 16, 0, 0);
    };

    f32x4 acc[8][4] = {};
    short8 a[4][2], blo[2][2], bhi[2][2];

    auto LDA4 = [&](short8 (&af)[4][2], int buf, int mbase) {
        const char* base = lds + buf * 65536;
        #pragma unroll
        for (int m = 0; m < 4; ++m)
            #pragma unroll
            for (int kk = 0; kk < 2; ++kk) {
                int row = wm * 128 + (mbase + m) * 16 + lr;
                int cc = (kk * 4 + lk) ^ (row & 7);
                af[m][kk] = *(const short8*)(base + row * 128 + cc * 16);
            }
    };
    auto LDB2 = [&](short8 (&bf)[2][2], int buf, int nbase) {
        const char* base = lds + buf * 65536 + 32768;
        #pragma unroll
        for (int n = 0; n < 2; ++n)
            #pragma unroll
            for (int kk = 0; kk < 2; ++kk) {
                int row = wn * 64 + (nbase + n) * 16 + lr;
                int cc = (kk * 4 + lk) ^ (row & 7);
                bf[n][kk] = *(const short8*)(base + row * 128 + cc * 16);
            }
    };

#define MMQ(AF, BF, MB, NB)                                                        \
    do {                                                                           \
        __builtin_amdgcn_s_setprio(1);                                             \
        _Pragma("unroll")                                                          \
        for (int m = 0; m < 4; ++m)                                                \
            _Pragma("unroll")                                                      \
            for (int n = 0; n < 2; ++n)                                            \
                _Pragma("unroll")                                                  \
                for (int kk = 0; kk < 2; ++kk)                                     \
                    acc[(MB) + m][(NB) + n] = __builtin_amdgcn_mfma_f32_16x16x32_bf16( \
                        AF[m][kk], BF[n][kk], acc[(MB) + m][(NB) + n], 0, 0, 0);   \
        __builtin_amdgcn_s_setprio(0);                                             \
    } while (0)

#define BAR() __builtin_amdgcn_s_barrier()
#define LGK0() asm volatile("s_waitcnt lgkmcnt(0)")
#define VM6() asm volatile("s_waitcnt vmcnt(6)" ::: "memory")

    // prologue: buf0 <- t0 (8 loads); buf1.B + buf1.A.h0 <- t1 (6 loads)
    STAGE(0, 0, 0, 0); STAGE(0, 0, 1, 0);
    STAGE(0, 1, 0, 0); STAGE(0, 1, 1, 0);
    STAGE(1, 1, 0, 1); STAGE(1, 1, 1, 1);
    STAGE(1, 0, 0, 1);
    VM6();   // buf0 landed; 6 loads (buf1.B + buf1.A.h0) in flight
    BAR();

    #pragma unroll 1
    for (int i = 0; i < NT / 2; ++i) {
        int t1 = 2 * i + 1;
        int t2 = 2 * i + 2; if (t2 > NT - 1) t2 = NT - 1;   // clamp keeps vmcnt uniform
        int t3 = 2 * i + 3; if (t3 > NT - 1) t3 = NT - 1;
        // P1: compute buf0 Q(0..3,0..1); stage buf1.A.h1 <- t1 (WAR-free since prev P7)
        LDA4(a, 0, 0); LDB2(blo, 0, 0);
        STAGE(1, 0, 1, t1);
        BAR(); LGK0();
        MMQ(a, blo, 0, 0);
        BAR();
        // P2: Q(0..3,2..3); no stage
        LDB2(bhi, 0, 2);
        BAR(); LGK0();
        MMQ(a, bhi, 0, 2);
        BAR();
        // P3: Q(4..7,2..3); stage buf0.B.h0 <- t2 (buf0.B free after P2)
        LDA4(a, 0, 4);
        STAGE(0, 1, 0, t2);
        BAR(); LGK0();
        MMQ(a, bhi, 4, 2);
        BAR();
        // P4: Q(4..7,0..1); stage buf0.B.h1 + buf0.A.h0 <- t2 (buf0.A free after P3); vmcnt(6) -> buf1 ready
        STAGE(0, 1, 1, t2); STAGE(0, 0, 0, t2);
        VM6();
        BAR();
        MMQ(a, blo, 4, 0);
        BAR();
        // P5: compute buf1 Q(0..3,0..1); stage buf0.A.h1 <- t2
        LDA4(a, 1, 0); LDB2(blo, 1, 0);
        STAGE(0, 0, 1, t2);
        BAR(); LGK0();
        MMQ(a, blo, 0, 0);
        BAR();
        // P6: Q(0..3,2..3); no stage
        LDB2(bhi, 1, 2);
        BAR(); LGK0();
        MMQ(a, bhi, 0, 2);
        BAR();
        // P7: Q(4..7,2..3); stage buf1.B.h0 <- t3 (buf1.B free after P6)
        LDA4(a, 1, 4);
        STAGE(1, 1, 0, t3);
        BAR(); LGK0();
        MMQ(a, bhi, 4, 2);
        BAR();
        // P8: Q(4..7,0..1); stage buf1.B.h1 + buf1.A.h0 <- t3 (buf1.A free after P7); vmcnt(6) -> buf0 ready
        STAGE(1, 1, 1, t3); STAGE(1, 0, 0, t3);
        VM6();
        BAR();
        MMQ(a, blo, 4, 0);
        BAR();
    }

    // epilogue: C/D map col=lane&15, row=(lane>>4)*4+j  [m89]
    #pragma unroll
    for (int n = 0; n < 4; ++n) {
        int col = colB0 + wn * 64 + n * 16 + lr;
        float bv = bias[col];
        #pragma unroll
        for (int m = 0; m < 8; ++m) {
            int row0 = rowA0 + wm * 128 + m * 16 + lk * 4;
            #pragma unroll
            for (int j = 0; j < 4; ++j) {
                out[(size_t)(row0 + j) * DOUT + col] = acc[m][n][j] + bv;
            }
        }
    }
#undef MMQ
#undef BAR
#undef LGK0
#undef VM6
}

extern "C" void kernel_launch(void* const* d_in, const int* in_sizes, int n_in,
                              void* d_out, int out_size, void* d_ws, size_t ws_size,
                              hipStream_t stream) {
    const float* x      = (const float*)d_in[0];
    const float* weight = (const float*)d_in[1];
    const float* bias   = (const float*)d_in[2];
    const float* A_buf  = (const float*)d_in[3];
    const float* B_buf  = (const float*)d_in[4];
    const int*   widx   = (const int*)d_in[5];
    float* out = (float*)d_out;

    __hip_bfloat16* xaug = (__hip_bfloat16*)d_ws;                                    // [8192][4224]
    __hip_bfloat16* waug = (__hip_bfloat16*)((char*)d_ws + (size_t)SDIM * KAUG * 2); // [4096][4224]
    // d_out doubles as scratch before gemm8 overwrites it:
    __hip_bfloat16* abf  = (__hip_bfloat16*)d_out;                    // [128][4096] bf16 = 1MB
    float*          part = (float*)((char*)d_out + (1 << 20));        // [4][8192][128] f32 = 16MB

    // x -> bf16 into xaug[:, 0:4096]
    {
        long total = (long)SDIM * DIN;
        cvt_f32_to_bf16_aug<<<(int)((total / 8 + 255) / 256), 256, 0, stream>>>(x, xaug, total);
    }
    // weight -> bf16 into waug[:, 0:4096]
    {
        long total = (long)DOUT * DIN;
        cvt_f32_to_bf16_aug<<<(int)((total / 8 + 255) / 256), 256, 0, stream>>>(weight, waug, total);
    }
    // B tail into waug[:, 4096:] + A -> bf16
    prep_small<<<2048 + 256, 256, 0, stream>>>(B_buf, A_buf, waug, abf);
    // XA_all partials (split-K x4)
    xa_gemm<<<64 * 4, 256, 0, stream>>>(xaug, abf, part);
    // reduce + adapter mask + scale -> xaug tail
    xa_reduce<<<(SDIM * 128) / 256, 256, 0, stream>>>(part, widx, xaug);
    // 8-phase 256^2 GEMM + bias
    gemm8<<<(SDIM / 256) * (DOUT / 256), 512, 0, stream>>>(xaug, waug, bias, out);
}